// Round 4
// baseline (1314.492 us; speedup 1.0000x reference)
//
#include <hip/hip_runtime.h>
#include <cstdint>

#define N_NODES 524288
#define E_EDGES 8388608
#define F_IN 128
#define HID 8
#define B_GRAPHS 64
#define NPG (N_NODES / B_GRAPHS)
#define NBLK 2048          // N_NODES / 256

// CSR build config
#define BUCKETS 1024       // coarse buckets (dst >> 9)
#define BSHIFT 9
#define BMASK 511
#define BUCKET_NODES 512   // nodes per bucket
#define ABLK 512           // phase-A blocks
#define ATHREADS 512
#define EPB (E_EDGES / ABLK)   // 16384 edges per phase-A block
#define CAP 9984           // per-bucket sort capacity (mean 8192, 20 sigma margin)

// ---------------- A1: per-block coarse histogram ----------------
__global__ void hist_kernel(const int* __restrict__ dst, int* __restrict__ M) {
    __shared__ int h[BUCKETS];
    int t = threadIdx.x;
    for (int j = t; j < BUCKETS; j += ATHREADS) h[j] = 0;
    __syncthreads();
    int base = blockIdx.x * EPB;
    #pragma unroll 4
    for (int k = 0; k < EPB / ATHREADS; ++k) {
        int d = dst[base + k * ATHREADS + t];
        atomicAdd(&h[d >> BSHIFT], 1);
    }
    __syncthreads();
    for (int j = t; j < BUCKETS; j += ATHREADS)
        M[(size_t)j * ABLK + blockIdx.x] = h[j];
}

// ---------------- A2: exclusive scan of each bucket row (over blocks) -------
__global__ void rowscan_kernel(int* __restrict__ M, int* __restrict__ btot) {
    __shared__ int tsum[256];
    int t = threadIdx.x;
    int* row = M + (size_t)blockIdx.x * ABLK;
    int v0 = row[t * 2], v1 = row[t * 2 + 1];
    int s = v0 + v1;
    tsum[t] = s;
    __syncthreads();
    for (int o = 1; o < 256; o <<= 1) {
        int y = (t >= o) ? tsum[t - o] : 0;
        __syncthreads();
        tsum[t] += y;
        __syncthreads();
    }
    int off = (t == 0) ? 0 : tsum[t - 1];
    row[t * 2] = off;
    row[t * 2 + 1] = off + v0;
    if (t == 255) btot[blockIdx.x] = off + s;
}

// ---------------- A3: exclusive scan of bucket totals -> bucket base --------
__global__ void basescan_kernel(const int* __restrict__ btot, int* __restrict__ base) {
    __shared__ int tsum[256];
    int t = threadIdx.x;
    int v[4], loc[4];
    int s = 0;
    #pragma unroll
    for (int k = 0; k < 4; ++k) {
        v[k] = btot[t * 4 + k];
        loc[k] = s;
        s += v[k];
    }
    tsum[t] = s;
    __syncthreads();
    for (int o = 1; o < 256; o <<= 1) {
        int y = (t >= o) ? tsum[t - o] : 0;
        __syncthreads();
        tsum[t] += y;
        __syncthreads();
    }
    int off = (t == 0) ? 0 : tsum[t - 1];
    #pragma unroll
    for (int k = 0; k < 4; ++k) base[t * 4 + k] = off + loc[k];
    if (t == 255) base[BUCKETS] = off + s;   // == E_EDGES
}

// ---------------- A4: bucket scatter via LDS cursors ----------
__global__ void scatter_kernel(const int* __restrict__ src, const int* __restrict__ dst,
                               const int* __restrict__ M, const int* __restrict__ base,
                               unsigned int* __restrict__ ebuf) {
    __shared__ int cur[BUCKETS];
    int t = threadIdx.x;
    for (int j = t; j < BUCKETS; j += ATHREADS)
        cur[j] = base[j] + M[(size_t)j * ABLK + blockIdx.x];
    __syncthreads();
    int eb = blockIdx.x * EPB;
    for (int k = 0; k < EPB / ATHREADS; ++k) {
        int e = eb + k * ATHREADS + t;
        int d = dst[e];
        int s = src[e];
        int p = atomicAdd(&cur[d >> BSHIFT], 1);
        ebuf[p] = ((unsigned int)(d & BMASK) << 19) | (unsigned int)s;
    }
}

// ------- B: in-LDS sort of each bucket segment by src>>10; also deg -> dis --
__global__ __launch_bounds__(256) void sortsrc_kernel(unsigned int* __restrict__ ebuf,
                                                      const int* __restrict__ base,
                                                      float* __restrict__ dis) {
    __shared__ unsigned int buf[CAP];       // 39936 B
    __shared__ unsigned short idx[CAP];     // 19968 B
    __shared__ int hist[512];               // 2048 B
    __shared__ int degh[512];               // 2048 B
    __shared__ int tsum[256];               // 1024 B  (total 65024 B)
    int t = threadIdx.x, b = blockIdx.x;
    int e0 = base[b];
    int n = base[b + 1] - e0;
    if (n > CAP) n = CAP;   // statistically unreachable (20 sigma)
    hist[t] = 0; hist[t + 256] = 0;
    degh[t] = 0; degh[t + 256] = 0;
    __syncthreads();
    for (int k = t; k < n; k += 256) {
        unsigned int w = ebuf[e0 + k];
        buf[k] = w;
        atomicAdd(&hist[(w & 0x7FFFFu) >> 10], 1);
        atomicAdd(&degh[w >> 19], 1);
    }
    __syncthreads();
    // exclusive scan of 512 src bins
    int v0 = hist[t * 2], v1 = hist[t * 2 + 1];
    int s = v0 + v1;
    tsum[t] = s;
    __syncthreads();
    for (int o = 1; o < 256; o <<= 1) {
        int y = (t >= o) ? tsum[t - o] : 0;
        __syncthreads();
        tsum[t] += y;
        __syncthreads();
    }
    int off = (t == 0) ? 0 : tsum[t - 1];
    hist[t * 2] = off;
    hist[t * 2 + 1] = off + v0;
    // dis from degree histogram (self-loop +1)
    int nb = b * BUCKET_NODES;
    dis[nb + t * 2]     = rsqrtf((float)degh[t * 2] + 1.0f);
    dis[nb + t * 2 + 1] = rsqrtf((float)degh[t * 2 + 1] + 1.0f);
    __syncthreads();
    // rank
    for (int k = t; k < n; k += 256) {
        int bin = (int)((buf[k] & 0x7FFFFu) >> 10);
        int p = atomicAdd(&hist[bin], 1);
        idx[p] = (unsigned short)k;
    }
    __syncthreads();
    // coalesced in-place writeback in sorted order
    for (int k = t; k < n; k += 256)
        ebuf[e0 + k] = buf[idx[k]];
}

// ---------------- hp' = (x @ W1) * dis  [N,128]x[128,8], prescaled ----------
__global__ void mm1_kernel(const float* __restrict__ x, const float* __restrict__ W1,
                           const float* __restrict__ dis, float* __restrict__ hp) {
    __shared__ float w[F_IN * HID];
    for (int t = threadIdx.x; t < F_IN * HID; t += blockDim.x) w[t] = W1[t];
    __syncthreads();
    int row = blockIdx.x * blockDim.x + threadIdx.x;
    if (row >= N_NODES) return;
    const float4* xr = (const float4*)(x + (size_t)row * F_IN);
    float acc[HID] = {0.f,0.f,0.f,0.f,0.f,0.f,0.f,0.f};
    #pragma unroll 8
    for (int it = 0; it < F_IN / 4; ++it) {
        float4 xv = xr[it];
        const float* wr = &w[it * 4 * HID];
        #pragma unroll
        for (int j = 0; j < HID; ++j)
            acc[j] += xv.x * wr[j] + xv.y * wr[HID + j] + xv.z * wr[2 * HID + j] + xv.w * wr[3 * HID + j];
    }
    float di = dis[row];
    float4* o = (float4*)(hp + (size_t)row * HID);
    o[0] = make_float4(acc[0]*di, acc[1]*di, acc[2]*di, acc[3]*di);
    o[1] = make_float4(acc[4]*di, acc[5]*di, acc[6]*di, acc[7]*di);
}

// ------- gather layer1 (push, LDS agg): hp2' = (relu(di*(agg+hp'self)+b1)@W2)*di
__global__ __launch_bounds__(256) void gatherA_kernel(const unsigned int* __restrict__ ebuf,
                                                      const int* __restrict__ base,
                                                      const float* __restrict__ dis,
                                                      const float* __restrict__ hp,
                                                      const float* __restrict__ b1v,
                                                      const float* __restrict__ W2,
                                                      float* __restrict__ hp2) {
    __shared__ float agg[BUCKET_NODES * 9];   // stride 9: bank-conflict-free
    __shared__ float w[HID * HID];
    __shared__ float bb[HID];
    int t = threadIdx.x, b = blockIdx.x;
    #pragma unroll
    for (int k = 0; k < 18; ++k) agg[t + k * 256] = 0.f;
    if (t < HID * HID) w[t] = W2[t];
    if (t < HID) bb[t] = b1v[t];
    __syncthreads();
    int e0 = base[b];
    int n = base[b + 1] - e0;
    for (int k = t; k < n; k += 256) {
        unsigned int e = ebuf[e0 + k];
        int s = (int)(e & 0x7FFFFu);
        int dlo = (int)(e >> 19);
        const float4* hv = (const float4*)(hp + (size_t)s * HID);
        float4 a = hv[0], c = hv[1];
        float* ag = agg + dlo * 9;
        atomicAdd(ag + 0, a.x); atomicAdd(ag + 1, a.y);
        atomicAdd(ag + 2, a.z); atomicAdd(ag + 3, a.w);
        atomicAdd(ag + 4, c.x); atomicAdd(ag + 5, c.y);
        atomicAdd(ag + 6, c.z); atomicAdd(ag + 7, c.w);
    }
    __syncthreads();
    #pragma unroll
    for (int h = 0; h < 2; ++h) {
        int node = t + h * 256;
        int g = b * BUCKET_NODES + node;
        float di = dis[g];
        const float4* hs = (const float4*)(hp + (size_t)g * HID);
        float4 h0 = hs[0], h1 = hs[1];
        const float* ag = agg + node * 9;
        float v[HID];
        v[0] = fmaxf(di * (ag[0] + h0.x) + bb[0], 0.f);
        v[1] = fmaxf(di * (ag[1] + h0.y) + bb[1], 0.f);
        v[2] = fmaxf(di * (ag[2] + h0.z) + bb[2], 0.f);
        v[3] = fmaxf(di * (ag[3] + h0.w) + bb[3], 0.f);
        v[4] = fmaxf(di * (ag[4] + h1.x) + bb[4], 0.f);
        v[5] = fmaxf(di * (ag[5] + h1.y) + bb[5], 0.f);
        v[6] = fmaxf(di * (ag[6] + h1.z) + bb[6], 0.f);
        v[7] = fmaxf(di * (ag[7] + h1.w) + bb[7], 0.f);
        float o[HID];
        #pragma unroll
        for (int j = 0; j < HID; ++j) {
            float sj = 0.f;
            #pragma unroll
            for (int k = 0; k < HID; ++k) sj += v[k] * w[k * HID + j];
            o[j] = sj * di;
        }
        float4* op = (float4*)(hp2 + (size_t)g * HID);
        op[0] = make_float4(o[0], o[1], o[2], o[3]);
        op[1] = make_float4(o[4], o[5], o[6], o[7]);
    }
}

// ------- gather layer2 (push): x2' = relu(di*(agg+hp2'self)+b2)*di ----------
__global__ __launch_bounds__(256) void gatherB_kernel(const unsigned int* __restrict__ ebuf,
                                                      const int* __restrict__ base,
                                                      const float* __restrict__ dis,
                                                      const float* __restrict__ hp2,
                                                      const float* __restrict__ b2v,
                                                      float* __restrict__ x2p) {
    __shared__ float agg[BUCKET_NODES * 9];
    __shared__ float bb[HID];
    int t = threadIdx.x, b = blockIdx.x;
    #pragma unroll
    for (int k = 0; k < 18; ++k) agg[t + k * 256] = 0.f;
    if (t < HID) bb[t] = b2v[t];
    __syncthreads();
    int e0 = base[b];
    int n = base[b + 1] - e0;
    for (int k = t; k < n; k += 256) {
        unsigned int e = ebuf[e0 + k];
        int s = (int)(e & 0x7FFFFu);
        int dlo = (int)(e >> 19);
        const float4* hv = (const float4*)(hp2 + (size_t)s * HID);
        float4 a = hv[0], c = hv[1];
        float* ag = agg + dlo * 9;
        atomicAdd(ag + 0, a.x); atomicAdd(ag + 1, a.y);
        atomicAdd(ag + 2, a.z); atomicAdd(ag + 3, a.w);
        atomicAdd(ag + 4, c.x); atomicAdd(ag + 5, c.y);
        atomicAdd(ag + 6, c.z); atomicAdd(ag + 7, c.w);
    }
    __syncthreads();
    #pragma unroll
    for (int h = 0; h < 2; ++h) {
        int node = t + h * 256;
        int g = b * BUCKET_NODES + node;
        float di = dis[g];
        const float4* hs = (const float4*)(hp2 + (size_t)g * HID);
        float4 h0 = hs[0], h1 = hs[1];
        const float* ag = agg + node * 9;
        float4 r0, r1;
        r0.x = fmaxf(di * (ag[0] + h0.x) + bb[0], 0.f) * di;
        r0.y = fmaxf(di * (ag[1] + h0.y) + bb[1], 0.f) * di;
        r0.z = fmaxf(di * (ag[2] + h0.z) + bb[2], 0.f) * di;
        r0.w = fmaxf(di * (ag[3] + h0.w) + bb[3], 0.f) * di;
        r1.x = fmaxf(di * (ag[4] + h1.x) + bb[4], 0.f) * di;
        r1.y = fmaxf(di * (ag[5] + h1.y) + bb[5], 0.f) * di;
        r1.z = fmaxf(di * (ag[6] + h1.z) + bb[6], 0.f) * di;
        r1.w = fmaxf(di * (ag[7] + h1.w) + bb[7], 0.f) * di;
        float4* xo = (float4*)(x2p + (size_t)g * HID);
        xo[0] = r0; xo[1] = r1;
    }
}

// ------- head: one block per graph; scan target's bucket for its in-edges ---
__global__ __launch_bounds__(256) void head_kernel(const int* __restrict__ tid,
                            const unsigned int* __restrict__ ebuf, const int* __restrict__ base,
                            const float* __restrict__ dis, const float* __restrict__ hp,
                            const float* __restrict__ x2p, const float* __restrict__ b1v,
                            const float* __restrict__ W3, const float* __restrict__ b3,
                            const float* __restrict__ Wl1, const float* __restrict__ bl1,
                            const float* __restrict__ Wl2, const float* __restrict__ bl2,
                            float* __restrict__ out) {
    __shared__ float red[9 * 256];
    int t = threadIdx.x, g = blockIdx.x;
    int tg = g * NPG + tid[g];
    int b = tg >> BSHIFT;
    int tlo = tg & BMASK;
    float w3[HID];
    #pragma unroll
    for (int j = 0; j < HID; ++j) w3[j] = W3[j];
    int e0 = base[b];
    int n = base[b + 1] - e0;
    float p1[HID] = {0.f,0.f,0.f,0.f,0.f,0.f,0.f,0.f};
    float p3 = 0.f;
    for (int k = t; k < n; k += 256) {
        unsigned int e = ebuf[e0 + k];
        if ((int)(e >> 19) != tlo) continue;
        int s = (int)(e & 0x7FFFFu);
        const float4* hv = (const float4*)(hp + (size_t)s * HID);
        float4 a = hv[0], c = hv[1];
        p1[0] += a.x; p1[1] += a.y; p1[2] += a.z; p1[3] += a.w;
        p1[4] += c.x; p1[5] += c.y; p1[6] += c.z; p1[7] += c.w;
        const float4* xv = (const float4*)(x2p + (size_t)s * HID);
        float4 xa = xv[0], xc = xv[1];
        p3 += xa.x*w3[0] + xa.y*w3[1] + xa.z*w3[2] + xa.w*w3[3]
            + xc.x*w3[4] + xc.y*w3[5] + xc.z*w3[6] + xc.w*w3[7];
    }
    #pragma unroll
    for (int j = 0; j < HID; ++j) red[j * 256 + t] = p1[j];
    red[8 * 256 + t] = p3;
    __syncthreads();
    for (int o = 128; o > 0; o >>= 1) {
        if (t < o) {
            #pragma unroll
            for (int j = 0; j < 9; ++j)
                red[j * 256 + t] += red[j * 256 + t + o];
        }
        __syncthreads();
    }
    if (t != 0) return;
    float dn = dis[tg];
    float f[17];
    #pragma unroll
    for (int j = 0; j < HID; ++j)
        f[j] = fmaxf(dn * (red[j * 256] + hp[(size_t)tg * HID + j]) + b1v[j], 0.f);
    float selfw3 = 0.f;
    #pragma unroll
    for (int j = 0; j < HID; ++j) {
        float x2v = x2p[(size_t)tg * HID + j];
        f[8 + j] = x2v / dn;             // x2' = x2*dis -> raw
        selfw3 += x2v * w3[j];
    }
    f[16] = fmaxf(dn * (red[8 * 256] + selfw3) + b3[0], 0.f);
    float o0 = bl2[0], o1 = bl2[1];
    #pragma unroll
    for (int j = 0; j < 16; ++j) {
        float z = bl1[j];
        #pragma unroll
        for (int k = 0; k < 17; ++k) z += f[k] * Wl1[k * 16 + j];
        z = fmaxf(z, 0.f);
        o0 += z * Wl2[j * 2 + 0];
        o1 += z * Wl2[j * 2 + 1];
    }
    out[g * 2 + 0] = o0;
    out[g * 2 + 1] = o1;
}

extern "C" void kernel_launch(void* const* d_in, const int* in_sizes, int n_in,
                              void* d_out, int out_size, void* d_ws, size_t ws_size,
                              hipStream_t stream) {
    const float* x  = (const float*)d_in[0];
    const int* ei   = (const int*)d_in[1];
    const int* src  = ei;
    const int* dst  = ei + E_EDGES;
    const int* tid  = (const int*)d_in[2];
    const float* W1 = (const float*)d_in[3];
    const float* b1 = (const float*)d_in[4];
    const float* W2 = (const float*)d_in[5];
    const float* b2 = (const float*)d_in[6];
    const float* W3 = (const float*)d_in[7];
    const float* b3 = (const float*)d_in[8];
    const float* Wl1 = (const float*)d_in[9];
    const float* bl1 = (const float*)d_in[10];
    const float* Wl2 = (const float*)d_in[11];
    const float* bl2 = (const float*)d_in[12];
    float* out = (float*)d_out;

    char* ws = (char*)d_ws;
    size_t off = 0;
    auto alloc = [&](size_t bytes) {
        void* p = ws + off;
        off += (bytes + 255) & ~(size_t)255;
        return p;
    };
    int* M        = (int*)alloc((size_t)BUCKETS * ABLK * 4);     // 2 MB
    int* btot     = (int*)alloc((size_t)BUCKETS * 4);
    int* base     = (int*)alloc((size_t)(BUCKETS + 1) * 4);
    float* dis    = (float*)alloc((size_t)N_NODES * 4);          // 2 MB
    unsigned int* ebuf = (unsigned int*)alloc((size_t)E_EDGES * 4); // 33.5 MB
    float* hp     = (float*)alloc((size_t)N_NODES * HID * 4);    // 16 MB
    float* hp2    = (float*)alloc((size_t)N_NODES * HID * 4);    // 16 MB
    float* x2p    = (float*)alloc((size_t)N_NODES * HID * 4);    // 16 MB

    hist_kernel<<<ABLK, ATHREADS, 0, stream>>>(dst, M);
    rowscan_kernel<<<BUCKETS, 256, 0, stream>>>(M, btot);
    basescan_kernel<<<1, 256, 0, stream>>>(btot, base);
    scatter_kernel<<<ABLK, ATHREADS, 0, stream>>>(src, dst, M, base, ebuf);
    sortsrc_kernel<<<BUCKETS, 256, 0, stream>>>(ebuf, base, dis);
    mm1_kernel<<<NBLK, 256, 0, stream>>>(x, W1, dis, hp);
    gatherA_kernel<<<BUCKETS, 256, 0, stream>>>(ebuf, base, dis, hp, b1, W2, hp2);
    gatherB_kernel<<<BUCKETS, 256, 0, stream>>>(ebuf, base, dis, hp2, b2, x2p);
    head_kernel<<<B_GRAPHS, 256, 0, stream>>>(tid, ebuf, base, dis, hp, x2p,
                                              b1, W3, b3, Wl1, bl1, Wl2, bl2, out);
}